// Round 5
// baseline (744.740 us; speedup 1.0000x reference)
//
#include <hip/hip_runtime.h>

#define BATCH 32
#define TIME  512
#define INF   512
#define HIDF  1024

#define MBT  128          // block tile: bt rows
#define NBH  128          // block tile: h cols
#define KCH  16           // k per chunk
#define NCH  (INF / KCH)  // 32 chunks
#define TILEF (MBT * KCH) // 2048 floats = 8 KB per buffer

// async global->LDS DMA, 16 B per lane, dst = wave-uniform base + lane*16
#define GLD16(g, l) __builtin_amdgcn_global_load_lds(                      \
    (const __attribute__((address_space(1))) void*)(g),                    \
    (__attribute__((address_space(3))) void*)(l), 16, 0, 0)

// ---------------------------------------------------------------------------
// Phase 1: hidden[bt][h] = (sum_k x[bt,k]*W[h,k]) + bias[h], bit-exact vs the
// XLA canonical order: ONE fp32 accumulator per output, fused FMA, k strictly
// ascending, ONE fp32 rounding for +bias.
//
// R11: conflict-free LDS verified (SQ_LDS_BANK_CONFLICT 1.678e7 -> 0) but
// dur only 247->240: neither DS pipe (164 us demand) nor VALU (~155 us) was
// saturated -> 76 us overlap deficit at 20% occupancy (2 blocks/CU).
// R12: __launch_bounds__(256,4). 4 blocks/CU fit exactly: LDS 4x32=128KB,
// VGPR 88*4=352<=512/SIMD, and the 1024-block grid = 4*256 CUs becomes
// fully co-resident (zero tail). ds_read chains of one wave now hide under
// 3 other waves' FMAs; per-chunk barriers of different blocks interleave.
//
// Conflict-free LDS scheme (R11, verified): within each 16-row window,
// global row 8*(s&1)+(s>>1) is staged into slot s (realized purely by
// permuting the per-lane GLOBAL source address of GLD16 - LDS dst stays
// linear), plus quad-XOR by (window&3). Octet ly reads slots (ly&1)+2r of
// window (ly>>1): bank group (ly&1)*16 + (g^(ly>>1))*4 -> 8 distinct
// quads, all 32 banks exactly once. The permutation composes so lane ly
// still gets exactly global rows wbt+8*ly+r with k-quads ascending:
// stores + FMA order unchanged.
// ---------------------------------------------------------------------------
__global__ __launch_bounds__(256, 4)
void snn_gemm_seqfma(const float* __restrict__ x, const float* __restrict__ W,
                     const float* __restrict__ bias, float* __restrict__ hidden) {
    __shared__ __align__(16) float xs[2 * TILEF];   // 16 KB
    __shared__ __align__(16) float ws[2 * TILEF];   // 16 KB

    const int tid = threadIdx.x;
    const int l   = tid & 63;
    const int wv  = __builtin_amdgcn_readfirstlane(tid >> 6);  // wave 0..3
    const int lx  = l & 7;           // h octet within wave sub-tile
    const int ly  = (l >> 3) & 7;    // bt octet within wave sub-tile
    const int bt0 = blockIdx.y * MBT;
    const int h0  = blockIdx.x * NBH;
    // wave sub-tile origin inside the 128x128 block tile
    const int wbt = 64 * (wv >> 1);  // bt offset: 0 or 64
    const int wh  = 64 * (wv & 1);   // h  offset: 0 or 64

    // ---- DMA staging: wave wv stages windows 2wv, 2wv+1 (16 rows each) ----
    // slot s in a window holds global row offset 8*(s&1) + (s>>1); quad
    // position q holds data quad q ^ (window&3).
    const int rl = l >> 2;                        // slot within window, 0..15
    const int qs = l & 3;                         // quad position, 0..3
    const int g0 = ((rl & 1) << 3) | (rl >> 1);   // global row offset for slot
    const int wA = 2 * wv;                        // window indices
    const int wB = 2 * wv + 1;
    const int rA = wA * 16 + g0;                  // global row (block-rel)
    const int rB = wB * 16 + g0;
    const int qA = qs ^ (wA & 3);
    const int qB = qs ^ (wB & 3);
    const float* xgA = x + (size_t)(bt0 + rA) * INF + qA * 4;
    const float* xgB = x + (size_t)(bt0 + rB) * INF + qB * 4;
    const float* wgA = W + (size_t)(h0 + rA) * INF + qA * 4;
    const float* wgB = W + (size_t)(h0 + rB) * INF + qB * 4;
    const int dOffA = (32 * wv) * KCH;        // wave-uniform LDS float offset
    const int dOffB = dOffA + 16 * KCH;

    // ---- prologue: stage chunk 0 into buffer 0 ----
    GLD16(xgA, xs + dOffA);
    GLD16(xgB, xs + dOffB);
    GLD16(wgA, ws + dOffA);
    GLD16(wgB, ws + dOffB);

    float acc[8][8];
    #pragma unroll
    for (int r = 0; r < 8; ++r)
        #pragma unroll
        for (int c = 0; c < 8; ++c) acc[r][c] = 0.0f;

    __syncthreads();   // drains vmcnt -> chunk 0 resident

    // per-lane read bases: octet o reads slots (o&1) + 2*idx of window (o>>1)
    const int xrow0 = wbt + (ly >> 1) * 16 + (ly & 1);
    const int wrow0 = wh  + (lx >> 1) * 16 + (lx & 1);
    const int xq = (ly >> 1) & 3;    // quad-XOR seen by this lane's x rows
    const int wq = (lx >> 1) & 3;    // quad-XOR seen by this lane's W rows

    for (int kc = 0; kc < NCH; ++kc) {
        const int p  = kc & 1;
        const int np = p ^ 1;

        // ---- issue next chunk's DMAs into the other buffer (async) ----
        if (kc + 1 < NCH) {
            const int so = (kc + 1) * KCH;    // float offset within a row
            float* xd = xs + np * TILEF;
            float* wd = ws + np * TILEF;
            GLD16(xgA + so, xd + dOffA);
            GLD16(xgB + so, xd + dOffB);
            GLD16(wgA + so, wd + dOffA);
            GLD16(wgB + so, wd + dOffB);
        }

        // ---- compute on current buffer: 4 groups of 4 k, g ascending ----
        const float* xb = xs + p * TILEF;
        const float* wb = ws + p * TILEF;
        #pragma unroll
        for (int g = 0; g < 4; ++g) {
            const int gx_ = (g ^ xq) * 4;     // storage quad for x rows
            const int gw_ = (g ^ wq) * 4;     // storage quad for W rows
            const float* xr = xb + xrow0 * KCH + gx_;
            const float* wr = wb + wrow0 * KCH + gw_;
            float4 xf[8], wf[8];
            #pragma unroll
            for (int r = 0; r < 8; ++r)
                xf[r] = *(const float4*)(xr + r * 2 * KCH);   // slot +2 rows
            #pragma unroll
            for (int c = 0; c < 8; ++c)
                wf[c] = *(const float4*)(wr + c * 2 * KCH);
            // xf[r] = data quads g of global row wbt+8ly+r (k ascending);
            // k strictly ascending within the group for every (r,c) chain
            #pragma unroll
            for (int r = 0; r < 8; ++r)
                #pragma unroll
                for (int c = 0; c < 8; ++c)
                    acc[r][c] = __fmaf_rn(xf[r].x, wf[c].x, acc[r][c]);
            #pragma unroll
            for (int r = 0; r < 8; ++r)
                #pragma unroll
                for (int c = 0; c < 8; ++c)
                    acc[r][c] = __fmaf_rn(xf[r].y, wf[c].y, acc[r][c]);
            #pragma unroll
            for (int r = 0; r < 8; ++r)
                #pragma unroll
                for (int c = 0; c < 8; ++c)
                    acc[r][c] = __fmaf_rn(xf[r].z, wf[c].z, acc[r][c]);
            #pragma unroll
            for (int r = 0; r < 8; ++r)
                #pragma unroll
                for (int c = 0; c < 8; ++c)
                    acc[r][c] = __fmaf_rn(xf[r].w, wf[c].w, acc[r][c]);
        }
        __syncthreads();   // all waves done with buf p; buf np's DMAs drained
    }

    // ---- epilogue: one fp32 rounding for bias, float4 stores ----
    float bv[8];
    #pragma unroll
    for (int c = 0; c < 8; ++c) bv[c] = bias[h0 + wh + lx * 8 + c];
    #pragma unroll
    for (int r = 0; r < 8; ++r) {
        float* orow = hidden + (size_t)(bt0 + wbt + ly * 8 + r) * HIDF
                             + h0 + wh + lx * 8;
        float4 o0, o1;
        o0.x = __fadd_rn(acc[r][0], bv[0]);
        o0.y = __fadd_rn(acc[r][1], bv[1]);
        o0.z = __fadd_rn(acc[r][2], bv[2]);
        o0.w = __fadd_rn(acc[r][3], bv[3]);
        o1.x = __fadd_rn(acc[r][4], bv[4]);
        o1.y = __fadd_rn(acc[r][5], bv[5]);
        o1.z = __fadd_rn(acc[r][6], bv[6]);
        o1.w = __fadd_rn(acc[r][7], bv[7]);
        ((float4*)orow)[0] = o0;
        ((float4*)orow)[1] = o1;
    }
}

// ---------------------------------------------------------------------------
// Phase 2: in-place LIF scan over t per (b,h) column, fp32:
//   mem = fl32(0.5*mem + h_t); spk = mem > 1.0f; hard reset to 0.
// Residual (total - gemm) is harness overhead + ~15-20 us scan; left as-is.
// ---------------------------------------------------------------------------
#define SEG 32

__global__ __launch_bounds__(64)
void snn_scan_np(float* __restrict__ io) {
    const int n = blockIdx.x * 64 + threadIdx.x;   // 0..32767
    const int b = n >> 10;
    const int h = n & 1023;
    float* p = io + (size_t)b * TIME * HIDF + h;

    float A[SEG], B[SEG];
    float mem = 0.0f;

    #pragma unroll
    for (int u = 0; u < SEG; ++u) A[u] = p[u * HIDF];

    for (int tb = 0; tb < TIME / SEG; tb += 2) {
        #pragma unroll
        for (int u = 0; u < SEG; ++u) B[u] = p[((tb + 1) * SEG + u) * HIDF];
        #pragma unroll
        for (int u = 0; u < SEG; ++u) {
            mem = __fadd_rn(__fmul_rn(0.5f, mem), A[u]);
            const bool s = mem > 1.0f;
            p[(tb * SEG + u) * HIDF] = s ? 1.0f : 0.0f;
            if (s) mem = 0.0f;
        }
        if (tb + 2 < TIME / SEG) {
            #pragma unroll
            for (int u = 0; u < SEG; ++u) A[u] = p[((tb + 2) * SEG + u) * HIDF];
        }
        #pragma unroll
        for (int u = 0; u < SEG; ++u) {
            mem = __fadd_rn(__fmul_rn(0.5f, mem), B[u]);
            const bool s = mem > 1.0f;
            p[((tb + 1) * SEG + u) * HIDF] = s ? 1.0f : 0.0f;
            if (s) mem = 0.0f;
        }
    }
}

extern "C" void kernel_launch(void* const* d_in, const int* in_sizes, int n_in,
                              void* d_out, int out_size, void* d_ws, size_t ws_size,
                              hipStream_t stream) {
    const float* x    = (const float*)d_in[0];   // [32, 512, 512]
    const float* W    = (const float*)d_in[1];   // [1024, 512]
    const float* bias = (const float*)d_in[2];   // [1024]
    float* out = (float*)d_out;                  // [32, 512, 1024]

    dim3 g1(HIDF / NBH, (BATCH * TIME) / MBT);   // (8, 128) = 1024 blocks
    snn_gemm_seqfma<<<g1, 256, 0, stream>>>(x, W, bias, out);

    snn_scan_np<<<(BATCH * HIDF) / 64, 64, 0, stream>>>(out);
}

// Round 6
// 315.290 us; speedup vs baseline: 2.3621x; 2.3621x over previous
//
#include <hip/hip_runtime.h>

#define BATCH 32
#define TIME  512
#define INF   512
#define HIDF  1024

#define MBT  128          // block tile: bt rows
#define NBH  128          // block tile: h cols
#define KCH  16           // k per chunk
#define NCH  (INF / KCH)  // 32 chunks

// async global->LDS DMA, 16 B per lane, dst = wave-uniform base + lane*16
#define GLD16(g, l) __builtin_amdgcn_global_load_lds(                      \
    (const __attribute__((address_space(1))) void*)(g),                    \
    (__attribute__((address_space(3))) void*)(l), 16, 0, 0)

// ---------------------------------------------------------------------------
// Phase 1: hidden[bt][h] = (sum_k x[bt,k]*W[h,k]) + bias[h], bit-exact vs the
// XLA canonical order: ONE fp32 accumulator per output, fused FMA, k strictly
// ascending, ONE fp32 rounding for +bias.
//
// R13: barrier-free wave-private staging. R11 ended at 240 us with DS pipe
// 68% / VALU 66% busy and neither saturated: the per-chunk __syncthreads
// forced the block's 4 waves into lockstep 32 times (aligned LDS bursts +
// reconvergence). Since cooperative staging was the ONLY reason for the
// barrier, each wave now stages its own 64 x-rows + 64 W-rows into a
// PRIVATE LDS region (lds[2][wave][x|w][64][16], 64 KB/block) and syncs
// only on its own DMAs via counted s_waitcnt vmcnt(8) (T4 idiom; 8 GLD16
// in flight for chunk kc+1, the wait retires chunk kc's 8). Waves free-run
// and de-correlate. Staging traffic doubles (L2-absorbed). Allocator facts
// (R9/R10/R12): only launch_bounds(256,2) avoids both the 64/128-VGPR
// clamps and spilling; 8x8 tile at ~VGPR 100 is the stable point.
//
// Conflict-free LDS scheme (R11, verified 0 conflicts), region-local form:
// within each 16-row window w of a wave's private region, global row
// 8*(s&1)+(s>>1) goes to slot s (pure GLOBAL-source permutation; LDS dst
// linear), quad position q holds data quad q ^ w. Octet o reads slots
// (o&1)+2r of window o>>1 at storage quad g^(o>>1): bank group
// (o&1)*16 + (g^(o>>1))*4 -> 8 distinct quads, all 32 banks exactly once.
// Region bases are 8KB-aligned so the analysis is unchanged. Lane octet
// ly receives exactly global rows 8*ly+r with k-quads ascending.
// ---------------------------------------------------------------------------

__device__ __forceinline__ void compute_chunk(const float* __restrict__ xb,
                                              const float* __restrict__ wb,
                                              int xrow0, int wrow0,
                                              int xq, int wq,
                                              float acc[8][8]) {
    #pragma unroll
    for (int g = 0; g < 4; ++g) {
        const int gx_ = (g ^ xq) * 4;     // storage quad for x rows
        const int gw_ = (g ^ wq) * 4;     // storage quad for W rows
        const float* xr = xb + xrow0 * KCH + gx_;
        const float* wr = wb + wrow0 * KCH + gw_;
        float4 xf[8], wf[8];
        #pragma unroll
        for (int r = 0; r < 8; ++r)
            xf[r] = *(const float4*)(xr + r * 2 * KCH);   // slot +2 rows
        #pragma unroll
        for (int c = 0; c < 8; ++c)
            wf[c] = *(const float4*)(wr + c * 2 * KCH);
        // k strictly ascending within the group for every (r,c) chain
        #pragma unroll
        for (int r = 0; r < 8; ++r)
            #pragma unroll
            for (int c = 0; c < 8; ++c)
                acc[r][c] = __fmaf_rn(xf[r].x, wf[c].x, acc[r][c]);
        #pragma unroll
        for (int r = 0; r < 8; ++r)
            #pragma unroll
            for (int c = 0; c < 8; ++c)
                acc[r][c] = __fmaf_rn(xf[r].y, wf[c].y, acc[r][c]);
        #pragma unroll
        for (int r = 0; r < 8; ++r)
            #pragma unroll
            for (int c = 0; c < 8; ++c)
                acc[r][c] = __fmaf_rn(xf[r].z, wf[c].z, acc[r][c]);
        #pragma unroll
        for (int r = 0; r < 8; ++r)
            #pragma unroll
            for (int c = 0; c < 8; ++c)
                acc[r][c] = __fmaf_rn(xf[r].w, wf[c].w, acc[r][c]);
    }
}

__global__ __launch_bounds__(256, 2)
void snn_gemm_seqfma(const float* __restrict__ x, const float* __restrict__ W,
                     const float* __restrict__ bias, float* __restrict__ hidden) {
    // [buf][wave][x|w][64 rows][16 floats] = 2*4*2*1024 floats = 64 KB
    __shared__ __align__(16) float lds[2][4][2][1024];

    const int tid = threadIdx.x;
    const int l   = tid & 63;
    const int wv  = __builtin_amdgcn_readfirstlane(tid >> 6);  // wave 0..3
    const int lx  = l & 7;           // h octet within wave sub-tile
    const int ly  = (l >> 3) & 7;    // bt octet within wave sub-tile
    const int bt0 = blockIdx.y * MBT;
    const int h0  = blockIdx.x * NBH;
    // wave sub-tile origin inside the 128x128 block tile
    const int wbt = 64 * (wv >> 1);  // bt offset: 0 or 64
    const int wh  = 64 * (wv & 1);   // h  offset: 0 or 64

    // ---- staging sources: 4 x-windows + 4 W-windows, all private to wv ----
    const int rl = l >> 2;                        // slot within window, 0..15
    const int qs = l & 3;                         // quad position, 0..3
    const int g0 = ((rl & 1) << 3) | (rl >> 1);   // global row offset for slot
    const float* px0 = x + (size_t)(bt0 + wbt +  0 + g0) * INF + ((qs ^ 0) * 4);
    const float* px1 = x + (size_t)(bt0 + wbt + 16 + g0) * INF + ((qs ^ 1) * 4);
    const float* px2 = x + (size_t)(bt0 + wbt + 32 + g0) * INF + ((qs ^ 2) * 4);
    const float* px3 = x + (size_t)(bt0 + wbt + 48 + g0) * INF + ((qs ^ 3) * 4);
    const float* pw0 = W + (size_t)(h0 + wh +  0 + g0) * INF + ((qs ^ 0) * 4);
    const float* pw1 = W + (size_t)(h0 + wh + 16 + g0) * INF + ((qs ^ 1) * 4);
    const float* pw2 = W + (size_t)(h0 + wh + 32 + g0) * INF + ((qs ^ 2) * 4);
    const float* pw3 = W + (size_t)(h0 + wh + 48 + g0) * INF + ((qs ^ 3) * 4);

    // ---- prologue: stage chunk 0 into buffer 0 (8 DMAs) ----
    GLD16(px0, &lds[0][wv][0][0 * 256]);
    GLD16(px1, &lds[0][wv][0][1 * 256]);
    GLD16(px2, &lds[0][wv][0][2 * 256]);
    GLD16(px3, &lds[0][wv][0][3 * 256]);
    GLD16(pw0, &lds[0][wv][1][0 * 256]);
    GLD16(pw1, &lds[0][wv][1][1 * 256]);
    GLD16(pw2, &lds[0][wv][1][2 * 256]);
    GLD16(pw3, &lds[0][wv][1][3 * 256]);

    float acc[8][8];
    #pragma unroll
    for (int r = 0; r < 8; ++r)
        #pragma unroll
        for (int c = 0; c < 8; ++c) acc[r][c] = 0.0f;

    // per-lane read bases within the wave-private region
    const int xrow0 = (ly >> 1) * 16 + (ly & 1);
    const int wrow0 = (lx >> 1) * 16 + (lx & 1);
    const int xq = (ly >> 1) & 3;    // quad-XOR seen by this lane's x rows
    const int wq = (lx >> 1) & 3;    // quad-XOR seen by this lane's W rows

    for (int kc = 0; kc < NCH - 1; ++kc) {
        const int p  = kc & 1;
        const int np = p ^ 1;
        const int so = (kc + 1) * KCH;    // float offset within a row

        // issue next chunk's 8 DMAs into the other private buffer (async)
        GLD16(px0 + so, &lds[np][wv][0][0 * 256]);
        GLD16(px1 + so, &lds[np][wv][0][1 * 256]);
        GLD16(px2 + so, &lds[np][wv][0][2 * 256]);
        GLD16(px3 + so, &lds[np][wv][0][3 * 256]);
        GLD16(pw0 + so, &lds[np][wv][1][0 * 256]);
        GLD16(pw1 + so, &lds[np][wv][1][1 * 256]);
        GLD16(pw2 + so, &lds[np][wv][1][2 * 256]);
        GLD16(pw3 + so, &lds[np][wv][1][3 * 256]);

        // retire exactly chunk kc's 8 DMAs (the newest 8 stay in flight);
        // no barrier: region is wave-private.
        asm volatile("s_waitcnt vmcnt(8)" ::: "memory");
        __builtin_amdgcn_sched_barrier(0);

        compute_chunk(&lds[p][wv][0][0], &lds[p][wv][1][0],
                      xrow0, wrow0, xq, wq, acc);
    }

    // last chunk: drain all, compute (NCH-1 is odd -> buffer 1)
    asm volatile("s_waitcnt vmcnt(0)" ::: "memory");
    __builtin_amdgcn_sched_barrier(0);
    compute_chunk(&lds[(NCH - 1) & 1][wv][0][0], &lds[(NCH - 1) & 1][wv][1][0],
                  xrow0, wrow0, xq, wq, acc);

    // ---- epilogue: one fp32 rounding for bias, float4 stores ----
    float bv[8];
    #pragma unroll
    for (int c = 0; c < 8; ++c) bv[c] = bias[h0 + wh + lx * 8 + c];
    #pragma unroll
    for (int r = 0; r < 8; ++r) {
        float* orow = hidden + (size_t)(bt0 + wbt + ly * 8 + r) * HIDF
                             + h0 + wh + lx * 8;
        float4 o0, o1;
        o0.x = __fadd_rn(acc[r][0], bv[0]);
        o0.y = __fadd_rn(acc[r][1], bv[1]);
        o0.z = __fadd_rn(acc[r][2], bv[2]);
        o0.w = __fadd_rn(acc[r][3], bv[3]);
        o1.x = __fadd_rn(acc[r][4], bv[4]);
        o1.y = __fadd_rn(acc[r][5], bv[5]);
        o1.z = __fadd_rn(acc[r][6], bv[6]);
        o1.w = __fadd_rn(acc[r][7], bv[7]);
        ((float4*)orow)[0] = o0;
        ((float4*)orow)[1] = o1;
    }
}

// ---------------------------------------------------------------------------
// Phase 2: in-place LIF scan over t per (b,h) column, fp32:
//   mem = fl32(0.5*mem + h_t); spk = mem > 1.0f; hard reset to 0.
// Residual (total - gemm) is harness overhead + ~15-20 us scan; left as-is.
// ---------------------------------------------------------------------------
#define SEG 32

__global__ __launch_bounds__(64)
void snn_scan_np(float* __restrict__ io) {
    const int n = blockIdx.x * 64 + threadIdx.x;   // 0..32767
    const int b = n >> 10;
    const int h = n & 1023;
    float* p = io + (size_t)b * TIME * HIDF + h;

    float A[SEG], B[SEG];
    float mem = 0.0f;

    #pragma unroll
    for (int u = 0; u < SEG; ++u) A[u] = p[u * HIDF];

    for (int tb = 0; tb < TIME / SEG; tb += 2) {
        #pragma unroll
        for (int u = 0; u < SEG; ++u) B[u] = p[((tb + 1) * SEG + u) * HIDF];
        #pragma unroll
        for (int u = 0; u < SEG; ++u) {
            mem = __fadd_rn(__fmul_rn(0.5f, mem), A[u]);
            const bool s = mem > 1.0f;
            p[(tb * SEG + u) * HIDF] = s ? 1.0f : 0.0f;
            if (s) mem = 0.0f;
        }
        if (tb + 2 < TIME / SEG) {
            #pragma unroll
            for (int u = 0; u < SEG; ++u) A[u] = p[((tb + 2) * SEG + u) * HIDF];
        }
        #pragma unroll
        for (int u = 0; u < SEG; ++u) {
            mem = __fadd_rn(__fmul_rn(0.5f, mem), B[u]);
            const bool s = mem > 1.0f;
            p[((tb + 1) * SEG + u) * HIDF] = s ? 1.0f : 0.0f;
            if (s) mem = 0.0f;
        }
    }
}

extern "C" void kernel_launch(void* const* d_in, const int* in_sizes, int n_in,
                              void* d_out, int out_size, void* d_ws, size_t ws_size,
                              hipStream_t stream) {
    const float* x    = (const float*)d_in[0];   // [32, 512, 512]
    const float* W    = (const float*)d_in[1];   // [1024, 512]
    const float* bias = (const float*)d_in[2];   // [1024]
    float* out = (float*)d_out;                  // [32, 512, 1024]

    dim3 g1(HIDF / NBH, (BATCH * TIME) / MBT);   // (8, 128) = 1024 blocks
    snn_gemm_seqfma<<<g1, 256, 0, stream>>>(x, W, bias, out);

    snn_scan_np<<<(BATCH * HIDF) / 64, 64, 0, stream>>>(out);
}